// Round 12
// baseline (1418.081 us; speedup 1.0000x reference)
//
#include <hip/hip_runtime.h>
#include <hip/hip_fp16.h>

constexpr int F      = 128;   // IN = H = CLS
constexpr int OUTF   = 64;
constexpr int NGRAPH = 128;
constexpr int POOL_CHUNK = 64;
constexpr int NP1    = 256;   // partition blocks (fixed, must match hist/part)
constexpr int NSTRIPE = 8;    // BN accumulator stripes (contention spread)

using half8 = __attribute__((ext_vector_type(8))) _Float16;
using f32x4 = __attribute__((ext_vector_type(4))) float;
using f32x8 = __attribute__((ext_vector_type(8))) float;

// ---------------- degree ----------------
__global__ __launch_bounds__(256) void k_deg_init(int* degi, int n) {
    int i = blockIdx.x * 256 + threadIdx.x;
    if (i < n) degi[i] = 0;
}

__global__ __launch_bounds__(256) void k_deg_edges(const int* __restrict__ dst, int* degi, int e) {
    int i = blockIdx.x * 256 + threadIdx.x;
    if (i < e) atomicAdd(&degi[dst[i]], 1);
}

// ---------------- generic 2-level exclusive scan ----------------
__global__ __launch_bounds__(256) void k_scan1(const int* __restrict__ src,
                                               int* __restrict__ out, int* __restrict__ bsum,
                                               float* __restrict__ dis, int n) {
    __shared__ int tmp[256];
    int i = blockIdx.x * 256 + threadIdx.x;
    int v = (i < n) ? src[i] : 0;
    if (dis && i < n) dis[i] = rsqrtf((float)(v + 1));  // +1 self-loop
    tmp[threadIdx.x] = v;
    __syncthreads();
    for (int s = 1; s < 256; s <<= 1) {
        int t = (threadIdx.x >= s) ? tmp[threadIdx.x - s] : 0;
        __syncthreads();
        tmp[threadIdx.x] += t;
        __syncthreads();
    }
    if (i < n) out[i] = tmp[threadIdx.x] - v;  // exclusive
    if (threadIdx.x == 255) bsum[blockIdx.x] = tmp[255];
}

__global__ __launch_bounds__(256) void k_scan2(int* bsum, int nb) {
    __shared__ int tmp[256];
    int i = threadIdx.x;
    int v = (i < nb) ? bsum[i] : 0;
    tmp[i] = v;
    __syncthreads();
    for (int s = 1; s < 256; s <<= 1) {
        int t = (i >= s) ? tmp[i - s] : 0;
        __syncthreads();
        tmp[i] += t;
        __syncthreads();
    }
    if (i < nb) bsum[i] = tmp[i] - v;  // exclusive
}

// node-offset finalize: offs, cursor, tail
__global__ __launch_bounds__(256) void k_scan3(const int* __restrict__ degi, int* __restrict__ off,
                                               const int* __restrict__ bsum, int* __restrict__ cursor, int n) {
    int i = blockIdx.x * 256 + threadIdx.x;
    if (i < n) {
        int o = off[i] + bsum[i >> 8];
        off[i] = o;
        cursor[i] = o;
        if (i == n - 1) off[n] = o + degi[i];
    }
}

// generic finalize (for histogram scan)
__global__ __launch_bounds__(256) void k_scan3b(int* __restrict__ arr, const int* __restrict__ bsum, int n) {
    int i = blockIdx.x * 256 + threadIdx.x;
    if (i < n) arr[i] += bsum[i >> 8];
}

// ---------------- radix partition by dst>>8 (bucket = 256 nodes) ----------------
__global__ __launch_bounds__(256) void k_hist(const int* __restrict__ dst,
                                              int* __restrict__ histg, int e, int nbuckets) {
    __shared__ int lh[256];
    lh[threadIdx.x] = 0;
    __syncthreads();
    const int chunk = (e + NP1 - 1) / NP1;
    const int i0 = blockIdx.x * chunk;
    const int i1 = min(i0 + chunk, e);
    for (int i = i0 + threadIdx.x; i < i1; i += 256)
        atomicAdd(&lh[dst[i] >> 8], 1);
    __syncthreads();
    if (threadIdx.x < nbuckets)
        histg[threadIdx.x * NP1 + blockIdx.x] = lh[threadIdx.x];
}

// partition: each (block,bucket) segment written contiguously
__global__ __launch_bounds__(256) void k_part(const int* __restrict__ src, const int* __restrict__ dst,
                                              const int* __restrict__ hbase,
                                              unsigned* __restrict__ tmp, int e, int nbuckets) {
    __shared__ int lc[256];
    if (threadIdx.x < nbuckets)
        lc[threadIdx.x] = hbase[threadIdx.x * NP1 + blockIdx.x];
    __syncthreads();
    const int chunk = (e + NP1 - 1) / NP1;
    const int i0 = blockIdx.x * chunk;
    const int i1 = min(i0 + chunk, e);
    for (int i = i0 + threadIdx.x; i < i1; i += 256) {
        int s = src[i], d = dst[i];
        int pos = atomicAdd(&lc[d >> 8], 1);
        tmp[pos] = ((unsigned)s << 8) | (unsigned)(d & 255);
    }
}

// exact per-node placement within L2-resident 256-node bucket region
__global__ __launch_bounds__(256) void k_scatB(const unsigned* __restrict__ tmp, const int* __restrict__ off,
                                               const float* __restrict__ dis, int* __restrict__ cursor,
                                               unsigned* __restrict__ csr4, int n) {
    int n0 = blockIdx.x << 8;
    int n1 = min(n0 + 256, n);
    int j1 = off[n1];
    for (int j = off[n0] + threadIdx.x; j < j1; j += 256) {
        unsigned v = tmp[j];
        int s = (int)(v >> 8);
        int d = n0 + (int)(v & 255u);
        float nm = dis[s] * dis[d];
        int pos = atomicAdd(&cursor[d], 1);
        unsigned short nh = __builtin_bit_cast(unsigned short, (_Float16)nm);
        csr4[pos] = (unsigned)s | ((unsigned)nh << 16);
    }
}

// ---------------- MFMA GEMM: h = fp16( act(in) @ W ), act = BN+ReLU of prev layer ----------------
template <typename T>
__global__ __launch_bounds__(256) void k_gemm_mfma(const T* __restrict__ in,
                                                   const float* __restrict__ w,
                                                   _Float16* __restrict__ out,
                                                   const float* __restrict__ scale,
                                                   const float* __restrict__ shift,
                                                   int n, int apply) {
    __shared__ _Float16 wt[F][F + 8];
    const int t = threadIdx.x;
#pragma unroll
    for (int r = 0; r < 64; ++r) {
        int idx = r * 256 + t;
        int k = idx >> 7, nn = idx & (F - 1);
        wt[nn][k] = (_Float16)w[idx];
    }
    __syncthreads();

    const int wave = t >> 6, lane = t & 63;
    const int row0 = blockIdx.x * 64 + wave * 16;
    const int arow = row0 + (lane & 15);
    const int kblk = (lane >> 4) * 8;
    const bool rvalid = arow < n;

    f32x4 acc[8];
#pragma unroll
    for (int nt = 0; nt < 8; ++nt) acc[nt] = (f32x4){0.f, 0.f, 0.f, 0.f};

#pragma unroll
    for (int ks = 0; ks < 4; ++ks) {
        const int k0 = ks * 32 + kblk;
        half8 afrag;
        if (rvalid) {
            float av[8];
            if constexpr (sizeof(T) == 4) {
                f32x8 v = *(const f32x8*)&in[(size_t)arow * F + k0];
#pragma unroll
                for (int i = 0; i < 8; ++i) av[i] = v[i];
            } else {
                half8 v = *(const half8*)&in[(size_t)arow * F + k0];
#pragma unroll
                for (int i = 0; i < 8; ++i) av[i] = (float)v[i];
            }
            if (apply) {
                f32x8 sc = *(const f32x8*)&scale[k0];
                f32x8 sh = *(const f32x8*)&shift[k0];
#pragma unroll
                for (int i = 0; i < 8; ++i) av[i] = fmaxf(av[i] * sc[i] + sh[i], 0.f);
            }
#pragma unroll
            for (int i = 0; i < 8; ++i) afrag[i] = (_Float16)av[i];
        } else {
#pragma unroll
            for (int i = 0; i < 8; ++i) afrag[i] = (_Float16)0.f;
        }
#pragma unroll
        for (int nt = 0; nt < 8; ++nt) {
            const half8 bfrag = *(const half8*)&wt[nt * 16 + (lane & 15)][k0];
            acc[nt] = __builtin_amdgcn_mfma_f32_16x16x32_f16(afrag, bfrag, acc[nt], 0, 0, 0);
        }
    }

    const int orow = row0 + (lane >> 4) * 4;
    const int ocol = lane & 15;
#pragma unroll
    for (int i = 0; i < 4; ++i) {
        if (orow + i < n) {
            _Float16* op = &out[(size_t)(orow + i) * F + ocol];
#pragma unroll
            for (int nt = 0; nt < 8; ++nt) op[nt * 16] = (_Float16)acc[nt][i];
        }
    }
}

// ---------------- aggregation + fused BN stats (per-wave, barrier-free) ----------------
// agg[i] = h[i]*dis[i]^2 + bias + sum_{e: dst=i} h[src_e] * norm_e
// stats: shfl-reduce within wave, striped global atomics (no LDS, no __syncthreads)
__global__ __launch_bounds__(256) void k_gcn_agg(const _Float16* __restrict__ h,
                                                 const unsigned* __restrict__ csr4,
                                                 const int* __restrict__ off,
                                                 const float* __restrict__ dis,
                                                 const float* __restrict__ bias,
                                                 _Float16* __restrict__ aggh,
                                                 float* __restrict__ statbuf, int n) {
    const int t = threadIdx.x;
    const int node = blockIdx.x * 16 + (t >> 4);
    const int f0 = (t & 15) << 3;
    float acc[8];
    if (node < n) {
        float d = dis[node];
        float dd = d * d;
        const half8 hv0 = *(const half8*)&h[(size_t)node * F + f0];
#pragma unroll
        for (int i = 0; i < 8; ++i) acc[i] = (float)hv0[i] * dd + bias[f0 + i];

        int k = off[node];
        const int k1 = off[node + 1];
        for (; k + 3 < k1; k += 4) {
            unsigned u0 = __builtin_nontemporal_load(&csr4[k]);
            unsigned u1 = __builtin_nontemporal_load(&csr4[k + 1]);
            unsigned u2 = __builtin_nontemporal_load(&csr4[k + 2]);
            unsigned u3 = __builtin_nontemporal_load(&csr4[k + 3]);
            int s0 = (int)(u0 & 0xFFFFu), s1 = (int)(u1 & 0xFFFFu);
            int s2 = (int)(u2 & 0xFFFFu), s3 = (int)(u3 & 0xFFFFu);
            float nm0 = (float)__builtin_bit_cast(_Float16, (unsigned short)(u0 >> 16));
            float nm1 = (float)__builtin_bit_cast(_Float16, (unsigned short)(u1 >> 16));
            float nm2 = (float)__builtin_bit_cast(_Float16, (unsigned short)(u2 >> 16));
            float nm3 = (float)__builtin_bit_cast(_Float16, (unsigned short)(u3 >> 16));
            const half8 a = *(const half8*)&h[(size_t)s0 * F + f0];
            const half8 b = *(const half8*)&h[(size_t)s1 * F + f0];
            const half8 c = *(const half8*)&h[(size_t)s2 * F + f0];
            const half8 e = *(const half8*)&h[(size_t)s3 * F + f0];
#pragma unroll
            for (int i = 0; i < 8; ++i) acc[i] += (float)a[i] * nm0;
#pragma unroll
            for (int i = 0; i < 8; ++i) acc[i] += (float)b[i] * nm1;
#pragma unroll
            for (int i = 0; i < 8; ++i) acc[i] += (float)c[i] * nm2;
#pragma unroll
            for (int i = 0; i < 8; ++i) acc[i] += (float)e[i] * nm3;
        }
        for (; k < k1; ++k) {
            unsigned u0 = __builtin_nontemporal_load(&csr4[k]);
            int s0 = (int)(u0 & 0xFFFFu);
            float nm0 = (float)__builtin_bit_cast(_Float16, (unsigned short)(u0 >> 16));
            const half8 a = *(const half8*)&h[(size_t)s0 * F + f0];
#pragma unroll
            for (int i = 0; i < 8; ++i) acc[i] += (float)a[i] * nm0;
        }
        half8 res;
#pragma unroll
        for (int i = 0; i < 8; ++i) res[i] = (_Float16)acc[i];
        *(half8*)&aggh[(size_t)node * F + f0] = res;
    } else {
#pragma unroll
        for (int i = 0; i < 8; ++i) acc[i] = 0.f;
    }

    // ---- fused stats: per-wave shfl reduce, striped global atomics ----
    float s[8], ss[8];
#pragma unroll
    for (int i = 0; i < 8; ++i) { s[i] = acc[i]; ss[i] = acc[i] * acc[i]; }
#pragma unroll
    for (int i = 0; i < 8; ++i) {
        s[i]  += __shfl_xor(s[i], 16);
        s[i]  += __shfl_xor(s[i], 32);
        ss[i] += __shfl_xor(ss[i], 16);
        ss[i] += __shfl_xor(ss[i], 32);
    }
    const int lane = t & 63, wv = t >> 6;
    if (lane < 16) {
        float* sp = &statbuf[((blockIdx.x + wv) & (NSTRIPE - 1)) * (2 * F)];
#pragma unroll
        for (int i = 0; i < 8; ++i) {
            unsafeAtomicAdd(&sp[f0 + i], s[i]);
            unsafeAtomicAdd(&sp[F + f0 + i], ss[i]);
        }
    }
}

// ---------------- batchnorm finalize (folds stripes, self-zeroing) ----------------
__global__ __launch_bounds__(256) void k_zero(float* p, int n) {
    int i = blockIdx.x * 256 + threadIdx.x;
    if (i < n) p[i] = 0.f;
}

__global__ __launch_bounds__(128) void k_stats_final(float* __restrict__ statbuf,
                                                     const float* __restrict__ g,
                                                     const float* __restrict__ b,
                                                     float* scale, float* shift, int n) {
    int t = threadIdx.x;
    float s = 0.f, q = 0.f;
#pragma unroll
    for (int st = 0; st < NSTRIPE; ++st) {
        s += statbuf[st * (2 * F) + t];
        q += statbuf[st * (2 * F) + F + t];
    }
    float mean = s / (float)n;
    float var = fmaxf(q / (float)n - mean * mean, 0.f);
    float inv = rsqrtf(var + 1e-5f);
    float sc = g[t] * inv;
    scale[t] = sc;
    shift[t] = b[t] - mean * sc;
#pragma unroll
    for (int st = 0; st < NSTRIPE; ++st) {
        statbuf[st * (2 * F) + t] = 0.f;
        statbuf[st * (2 * F) + F + t] = 0.f;
    }
}

// ---------------- pooling (batch is sorted, fp16 agg) ----------------
__global__ __launch_bounds__(128) void k_pool(const _Float16* __restrict__ aggh,
                                              const int* __restrict__ batch,
                                              const float* __restrict__ scale,
                                              const float* __restrict__ shift,
                                              float* pooled, float* cnt, int n) {
    int t = threadIdx.x;
    int row0 = blockIdx.x * POOL_CHUNK;
    if (row0 >= n) return;
    int rend = min(row0 + POOL_CHUNK, n);
    float sc = scale[t], sh = shift[t];
    int gcur = batch[row0];
    float acc = 0.f, c = 0.f;
    for (int r = row0; r < rend; ++r) {
        int g = batch[r];
        if (g != gcur) {
            unsafeAtomicAdd(&pooled[gcur * F + t], acc);
            if (t == 0) unsafeAtomicAdd(&cnt[gcur], c);
            acc = 0.f; c = 0.f; gcur = g;
        }
        float v = fmaxf((float)aggh[(size_t)r * F + t] * sc + sh, 0.f);
        acc += v; c += 1.f;
    }
    unsafeAtomicAdd(&pooled[gcur * F + t], acc);
    if (t == 0) unsafeAtomicAdd(&cnt[gcur], c);
}

// ---------------- final MLP ----------------
__global__ __launch_bounds__(128) void k_mlp(const float* __restrict__ pooled,
                                             const float* __restrict__ cnt,
                                             const float* __restrict__ l1w, const float* __restrict__ l1b,
                                             const float* __restrict__ l2w, const float* __restrict__ l2b,
                                             const float* __restrict__ fcw, const float* __restrict__ fcb,
                                             float* __restrict__ out) {
    __shared__ float pr[F], h1[F], h2[OUTF];
    int g = blockIdx.x, t = threadIdx.x;
    float c = fmaxf(cnt[g], 1.f);
    pr[t] = pooled[g * F + t] / c;
    __syncthreads();
    float a = l1b[t];
#pragma unroll 4
    for (int k = 0; k < F; ++k) a += pr[k] * l1w[k * F + t];
    h1[t] = a;
    __syncthreads();
    if (t < OUTF) {
        float b = l2b[t];
#pragma unroll 4
        for (int k = 0; k < F; ++k) b += h1[k] * l2w[k * OUTF + t];
        h2[t] = b;
    }
    __syncthreads();
    if (t < OUTF) {
        float o = fcb[t];
#pragma unroll 4
        for (int k = 0; k < OUTF; ++k) o += h2[k] * fcw[k * OUTF + t];
        out[g * OUTF + t] = (o >= 0.f) ? o : 0.01f * o;
    }
}

// ---------------- launcher ----------------
extern "C" void kernel_launch(void* const* d_in, const int* in_sizes, int n_in,
                              void* d_out, int out_size, void* d_ws, size_t ws_size,
                              hipStream_t stream) {
    const float* x      = (const float*)d_in[0];
    const int*   ei     = (const int*)d_in[1];
    const int*   batch  = (const int*)d_in[2];
    const float* convw[3] = {(const float*)d_in[3], (const float*)d_in[5], (const float*)d_in[7]};
    const float* convb[3] = {(const float*)d_in[4], (const float*)d_in[6], (const float*)d_in[8]};
    const float* bng[3]   = {(const float*)d_in[9],  (const float*)d_in[11], (const float*)d_in[13]};
    const float* bnb[3]   = {(const float*)d_in[10], (const float*)d_in[12], (const float*)d_in[14]};
    const float* l1w = (const float*)d_in[15]; const float* l1b = (const float*)d_in[16];
    const float* l2w = (const float*)d_in[17]; const float* l2b = (const float*)d_in[18];
    const float* fcw = (const float*)d_in[19]; const float* fcb = (const float*)d_in[20];

    const int N = in_sizes[2];
    const int E = in_sizes[1] / 2;
    const int* srcp = ei;
    const int* dstp = ei + E;
    const int NB = (N + 255) / 256;          // node-scan blocks (196)
    const int NBUCK = (N + 255) >> 8;        // 256-node buckets (196)
    const int HLEN = NBUCK * NP1;            // histogram length (50176)
    const int HB = (HLEN + 255) / 256;       // hist-scan blocks (196, <=256)

    char* wsp = (char*)d_ws;
    size_t off_b = 0;
    auto alloc = [&](size_t bytes) -> void* {
        void* p = wsp + off_b;
        off_b += (bytes + 255) / 256 * 256;
        return p;
    };
    int*      degi    = (int*)alloc((size_t)N * 4);
    float*    dis     = (float*)alloc((size_t)N * 4);
    int*      offs    = (int*)alloc((size_t)(N + 1) * 4);
    int*      cursor  = (int*)alloc((size_t)N * 4);
    int*      bsum    = (int*)alloc(256 * 4);
    int*      hbase   = (int*)alloc((size_t)HLEN * 4);
    int*      bsum2   = (int*)alloc(256 * 4);
    unsigned* tmp     = (unsigned*)alloc((size_t)E * 4);
    unsigned* csr4    = (unsigned*)alloc((size_t)E * 4);
    _Float16* hbuf    = (_Float16*)alloc((size_t)N * F * 2);
    _Float16* aggh    = (_Float16*)alloc((size_t)N * F * 2);
    float*    statbuf = (float*)alloc(NSTRIPE * 2 * F * 4);
    float*    scale   = (float*)alloc(F * 4);
    float*    shift   = (float*)alloc(F * 4);
    float*    pooled  = (float*)alloc(NGRAPH * F * 4);
    float*    cnt     = (float*)alloc(NGRAPH * 4);  // contiguous after pooled
    (void)ws_size; (void)n_in; (void)out_size;

    // ---- CSR build: degree -> offsets; radix partition -> exact placement ----
    k_deg_init<<<NB, 256, 0, stream>>>(degi, N);
    k_deg_edges<<<(E + 255) / 256, 256, 0, stream>>>(dstp, degi, E);
    k_scan1<<<NB, 256, 0, stream>>>(degi, offs, bsum, dis, N);
    k_scan2<<<1, 256, 0, stream>>>(bsum, NB);
    k_scan3<<<NB, 256, 0, stream>>>(degi, offs, bsum, cursor, N);

    k_hist<<<NP1, 256, 0, stream>>>(dstp, hbase, E, NBUCK);
    k_scan1<<<HB, 256, 0, stream>>>(hbase, hbase, bsum2, nullptr, HLEN);
    k_scan2<<<1, 256, 0, stream>>>(bsum2, HB);
    k_scan3b<<<HB, 256, 0, stream>>>(hbase, bsum2, HLEN);
    k_part<<<NP1, 256, 0, stream>>>(srcp, dstp, hbase, tmp, E, NBUCK);
    k_scatB<<<NBUCK, 256, 0, stream>>>(tmp, offs, dis, cursor, csr4, N);

    // zero striped BN accumulators once; k_stats_final re-zeroes them per layer
    k_zero<<<(NSTRIPE * 2 * F + 255) / 256, 256, 0, stream>>>(statbuf, NSTRIPE * 2 * F);

    // ---- 3 GCN layers ----
    for (int l = 0; l < 3; ++l) {
        if (l == 0)
            k_gemm_mfma<float><<<(N + 63) / 64, 256, 0, stream>>>(
                x, convw[l], hbuf, scale, shift, N, 0);
        else
            k_gemm_mfma<_Float16><<<(N + 63) / 64, 256, 0, stream>>>(
                aggh, convw[l], hbuf, scale, shift, N, 1);
        k_gcn_agg<<<(N + 15) / 16, 256, 0, stream>>>(hbuf, csr4, offs, dis, convb[l], aggh, statbuf, N);
        k_stats_final<<<1, 128, 0, stream>>>(statbuf, bng[l], bnb[l], scale, shift, N);
    }

    k_zero<<<(NGRAPH * F + NGRAPH + 255) / 256, 256, 0, stream>>>(pooled, NGRAPH * F + NGRAPH);
    k_pool<<<(N + POOL_CHUNK - 1) / POOL_CHUNK, 128, 0, stream>>>(aggh, batch, scale, shift, pooled, cnt, N);
    k_mlp<<<NGRAPH, 128, 0, stream>>>(pooled, cnt, l1w, l1b, l2w, l2b, fcw, fcb, (float*)d_out);
}

// Round 13
// 591.202 us; speedup vs baseline: 2.3986x; 2.3986x over previous
//
#include <hip/hip_runtime.h>
#include <hip/hip_fp16.h>

constexpr int F      = 128;   // IN = H = CLS
constexpr int OUTF   = 64;
constexpr int NGRAPH = 128;
constexpr int POOL_CHUNK = 64;
constexpr int NP1    = 256;   // partition blocks (fixed, must match hist/part)
constexpr int STAT_ROWS = 128;  // rows per stats block

using half8 = __attribute__((ext_vector_type(8))) _Float16;
using f32x4 = __attribute__((ext_vector_type(4))) float;
using f32x8 = __attribute__((ext_vector_type(8))) float;

// ---------------- degree ----------------
__global__ __launch_bounds__(256) void k_deg_init(int* degi, int n) {
    int i = blockIdx.x * 256 + threadIdx.x;
    if (i < n) degi[i] = 0;
}

__global__ __launch_bounds__(256) void k_deg_edges(const int* __restrict__ dst, int* degi, int e) {
    int i = blockIdx.x * 256 + threadIdx.x;
    if (i < e) atomicAdd(&degi[dst[i]], 1);
}

// ---------------- generic 2-level exclusive scan ----------------
__global__ __launch_bounds__(256) void k_scan1(const int* __restrict__ src,
                                               int* __restrict__ out, int* __restrict__ bsum,
                                               float* __restrict__ dis, int n) {
    __shared__ int tmp[256];
    int i = blockIdx.x * 256 + threadIdx.x;
    int v = (i < n) ? src[i] : 0;
    if (dis && i < n) dis[i] = rsqrtf((float)(v + 1));  // +1 self-loop
    tmp[threadIdx.x] = v;
    __syncthreads();
    for (int s = 1; s < 256; s <<= 1) {
        int t = (threadIdx.x >= s) ? tmp[threadIdx.x - s] : 0;
        __syncthreads();
        tmp[threadIdx.x] += t;
        __syncthreads();
    }
    if (i < n) out[i] = tmp[threadIdx.x] - v;  // exclusive
    if (threadIdx.x == 255) bsum[blockIdx.x] = tmp[255];
}

__global__ __launch_bounds__(256) void k_scan2(int* bsum, int nb) {
    __shared__ int tmp[256];
    int i = threadIdx.x;
    int v = (i < nb) ? bsum[i] : 0;
    tmp[i] = v;
    __syncthreads();
    for (int s = 1; s < 256; s <<= 1) {
        int t = (i >= s) ? tmp[i - s] : 0;
        __syncthreads();
        tmp[i] += t;
        __syncthreads();
    }
    if (i < nb) bsum[i] = tmp[i] - v;  // exclusive
}

// node-offset finalize: offs, cursor, tail
__global__ __launch_bounds__(256) void k_scan3(const int* __restrict__ degi, int* __restrict__ off,
                                               const int* __restrict__ bsum, int* __restrict__ cursor, int n) {
    int i = blockIdx.x * 256 + threadIdx.x;
    if (i < n) {
        int o = off[i] + bsum[i >> 8];
        off[i] = o;
        cursor[i] = o;
        if (i == n - 1) off[n] = o + degi[i];
    }
}

// generic finalize (for histogram scan)
__global__ __launch_bounds__(256) void k_scan3b(int* __restrict__ arr, const int* __restrict__ bsum, int n) {
    int i = blockIdx.x * 256 + threadIdx.x;
    if (i < n) arr[i] += bsum[i >> 8];
}

// ---------------- radix partition by dst>>8 (bucket = 256 nodes) ----------------
__global__ __launch_bounds__(256) void k_hist(const int* __restrict__ dst,
                                              int* __restrict__ histg, int e, int nbuckets) {
    __shared__ int lh[256];
    lh[threadIdx.x] = 0;
    __syncthreads();
    const int chunk = (e + NP1 - 1) / NP1;
    const int i0 = blockIdx.x * chunk;
    const int i1 = min(i0 + chunk, e);
    for (int i = i0 + threadIdx.x; i < i1; i += 256)
        atomicAdd(&lh[dst[i] >> 8], 1);
    __syncthreads();
    if (threadIdx.x < nbuckets)
        histg[threadIdx.x * NP1 + blockIdx.x] = lh[threadIdx.x];
}

// partition: each (block,bucket) segment written contiguously
__global__ __launch_bounds__(256) void k_part(const int* __restrict__ src, const int* __restrict__ dst,
                                              const int* __restrict__ hbase,
                                              unsigned* __restrict__ tmp, int e, int nbuckets) {
    __shared__ int lc[256];
    if (threadIdx.x < nbuckets)
        lc[threadIdx.x] = hbase[threadIdx.x * NP1 + blockIdx.x];
    __syncthreads();
    const int chunk = (e + NP1 - 1) / NP1;
    const int i0 = blockIdx.x * chunk;
    const int i1 = min(i0 + chunk, e);
    for (int i = i0 + threadIdx.x; i < i1; i += 256) {
        int s = src[i], d = dst[i];
        int pos = atomicAdd(&lc[d >> 8], 1);
        tmp[pos] = ((unsigned)s << 8) | (unsigned)(d & 255);
    }
}

// exact per-node placement within L2-resident 256-node bucket region
__global__ __launch_bounds__(256) void k_scatB(const unsigned* __restrict__ tmp, const int* __restrict__ off,
                                               const float* __restrict__ dis, int* __restrict__ cursor,
                                               unsigned* __restrict__ csr4, int n) {
    int n0 = blockIdx.x << 8;
    int n1 = min(n0 + 256, n);
    int j1 = off[n1];
    for (int j = off[n0] + threadIdx.x; j < j1; j += 256) {
        unsigned v = tmp[j];
        int s = (int)(v >> 8);
        int d = n0 + (int)(v & 255u);
        float nm = dis[s] * dis[d];
        int pos = atomicAdd(&cursor[d], 1);
        unsigned short nh = __builtin_bit_cast(unsigned short, (_Float16)nm);
        csr4[pos] = (unsigned)s | ((unsigned)nh << 16);
    }
}

// ---------------- MFMA GEMM: h = fp16( act(in) @ W ), act = BN+ReLU of prev layer ----------------
template <typename T>
__global__ __launch_bounds__(256) void k_gemm_mfma(const T* __restrict__ in,
                                                   const float* __restrict__ w,
                                                   _Float16* __restrict__ out,
                                                   const float* __restrict__ scale,
                                                   const float* __restrict__ shift,
                                                   int n, int apply) {
    __shared__ _Float16 wt[F][F + 8];
    const int t = threadIdx.x;
#pragma unroll
    for (int r = 0; r < 64; ++r) {
        int idx = r * 256 + t;
        int k = idx >> 7, nn = idx & (F - 1);
        wt[nn][k] = (_Float16)w[idx];
    }
    __syncthreads();

    const int wave = t >> 6, lane = t & 63;
    const int row0 = blockIdx.x * 64 + wave * 16;
    const int arow = row0 + (lane & 15);
    const int kblk = (lane >> 4) * 8;
    const bool rvalid = arow < n;

    f32x4 acc[8];
#pragma unroll
    for (int nt = 0; nt < 8; ++nt) acc[nt] = (f32x4){0.f, 0.f, 0.f, 0.f};

#pragma unroll
    for (int ks = 0; ks < 4; ++ks) {
        const int k0 = ks * 32 + kblk;
        half8 afrag;
        if (rvalid) {
            float av[8];
            if constexpr (sizeof(T) == 4) {
                f32x8 v = *(const f32x8*)&in[(size_t)arow * F + k0];
#pragma unroll
                for (int i = 0; i < 8; ++i) av[i] = v[i];
            } else {
                half8 v = *(const half8*)&in[(size_t)arow * F + k0];
#pragma unroll
                for (int i = 0; i < 8; ++i) av[i] = (float)v[i];
            }
            if (apply) {
                f32x8 sc = *(const f32x8*)&scale[k0];
                f32x8 sh = *(const f32x8*)&shift[k0];
#pragma unroll
                for (int i = 0; i < 8; ++i) av[i] = fmaxf(av[i] * sc[i] + sh[i], 0.f);
            }
#pragma unroll
            for (int i = 0; i < 8; ++i) afrag[i] = (_Float16)av[i];
        } else {
#pragma unroll
            for (int i = 0; i < 8; ++i) afrag[i] = (_Float16)0.f;
        }
#pragma unroll
        for (int nt = 0; nt < 8; ++nt) {
            const half8 bfrag = *(const half8*)&wt[nt * 16 + (lane & 15)][k0];
            acc[nt] = __builtin_amdgcn_mfma_f32_16x16x32_f16(afrag, bfrag, acc[nt], 0, 0, 0);
        }
    }

    const int orow = row0 + (lane >> 4) * 4;
    const int ocol = lane & 15;
#pragma unroll
    for (int i = 0; i < 4; ++i) {
        if (orow + i < n) {
            _Float16* op = &out[(size_t)(orow + i) * F + ocol];
#pragma unroll
            for (int nt = 0; nt < 8; ++nt) op[nt * 16] = (_Float16)acc[nt][i];
        }
    }
}

// ---------------- aggregation: pure gather-reduce (4x unrolled), fp16 h -> fp16 agg ----------------
__global__ __launch_bounds__(256) void k_gcn_agg(const _Float16* __restrict__ h,
                                                 const unsigned* __restrict__ csr4,
                                                 const int* __restrict__ off,
                                                 const float* __restrict__ dis,
                                                 const float* __restrict__ bias,
                                                 _Float16* __restrict__ aggh, int n) {
    const int t = threadIdx.x;
    const int node = blockIdx.x * 16 + (t >> 4);
    if (node >= n) return;
    const int f0 = (t & 15) << 3;
    float d = dis[node];
    float dd = d * d;
    const half8 hv0 = *(const half8*)&h[(size_t)node * F + f0];
    float acc[8];
#pragma unroll
    for (int i = 0; i < 8; ++i) acc[i] = (float)hv0[i] * dd + bias[f0 + i];

    int k = off[node];
    const int k1 = off[node + 1];
    for (; k + 3 < k1; k += 4) {
        unsigned u0 = __builtin_nontemporal_load(&csr4[k]);
        unsigned u1 = __builtin_nontemporal_load(&csr4[k + 1]);
        unsigned u2 = __builtin_nontemporal_load(&csr4[k + 2]);
        unsigned u3 = __builtin_nontemporal_load(&csr4[k + 3]);
        int s0 = (int)(u0 & 0xFFFFu), s1 = (int)(u1 & 0xFFFFu);
        int s2 = (int)(u2 & 0xFFFFu), s3 = (int)(u3 & 0xFFFFu);
        float nm0 = (float)__builtin_bit_cast(_Float16, (unsigned short)(u0 >> 16));
        float nm1 = (float)__builtin_bit_cast(_Float16, (unsigned short)(u1 >> 16));
        float nm2 = (float)__builtin_bit_cast(_Float16, (unsigned short)(u2 >> 16));
        float nm3 = (float)__builtin_bit_cast(_Float16, (unsigned short)(u3 >> 16));
        const half8 a = *(const half8*)&h[(size_t)s0 * F + f0];
        const half8 b = *(const half8*)&h[(size_t)s1 * F + f0];
        const half8 c = *(const half8*)&h[(size_t)s2 * F + f0];
        const half8 e = *(const half8*)&h[(size_t)s3 * F + f0];
#pragma unroll
        for (int i = 0; i < 8; ++i) acc[i] += (float)a[i] * nm0;
#pragma unroll
        for (int i = 0; i < 8; ++i) acc[i] += (float)b[i] * nm1;
#pragma unroll
        for (int i = 0; i < 8; ++i) acc[i] += (float)c[i] * nm2;
#pragma unroll
        for (int i = 0; i < 8; ++i) acc[i] += (float)e[i] * nm3;
    }
    for (; k < k1; ++k) {
        unsigned u0 = __builtin_nontemporal_load(&csr4[k]);
        int s0 = (int)(u0 & 0xFFFFu);
        float nm0 = (float)__builtin_bit_cast(_Float16, (unsigned short)(u0 >> 16));
        const half8 a = *(const half8*)&h[(size_t)s0 * F + f0];
#pragma unroll
        for (int i = 0; i < 8; ++i) acc[i] += (float)a[i] * nm0;
    }
    half8 res;
#pragma unroll
    for (int i = 0; i < 8; ++i) res[i] = (_Float16)acc[i];
    *(half8*)&aggh[(size_t)node * F + f0] = res;
}

// ---------------- batchnorm stats: streaming column reduce (256 thr, 128 rows/block) ----------------
__global__ __launch_bounds__(256) void k_stats(const _Float16* __restrict__ aggh,
                                               float* __restrict__ sum,
                                               float* __restrict__ sumsq, int n) {
    __shared__ float ls[F], lq[F];
    const int t = threadIdx.x;
    const int col = t & (F - 1);
    const int row0 = blockIdx.x * STAT_ROWS + (t >> 7);  // two row-streams per block
    const int rend = min(blockIdx.x * STAT_ROWS + STAT_ROWS, n);
    float s = 0.f, q = 0.f;
    for (int r = row0; r < rend; r += 2) {
        float v = (float)aggh[(size_t)r * F + col];
        s += v; q += v * v;
    }
    if (t >= F) { ls[col] = s; lq[col] = q; }
    __syncthreads();
    if (t < F) {
        s += ls[col]; q += lq[col];
        unsafeAtomicAdd(&sum[col], s);
        unsafeAtomicAdd(&sumsq[col], q);
    }
}

// ---------------- batchnorm finalize (self-zeroing accumulators) ----------------
__global__ __launch_bounds__(256) void k_zero(float* p, int n) {
    int i = blockIdx.x * 256 + threadIdx.x;
    if (i < n) p[i] = 0.f;
}

__global__ __launch_bounds__(128) void k_stats_final(float* __restrict__ sum,
                                                     float* __restrict__ sumsq,
                                                     const float* __restrict__ g,
                                                     const float* __restrict__ b,
                                                     float* scale, float* shift, int n) {
    int t = threadIdx.x;
    float mean = sum[t] / (float)n;
    float var = fmaxf(sumsq[t] / (float)n - mean * mean, 0.f);
    float inv = rsqrtf(var + 1e-5f);
    float sc = g[t] * inv;
    scale[t] = sc;
    shift[t] = b[t] - mean * sc;
    sum[t] = 0.f;     // ready for next layer
    sumsq[t] = 0.f;
}

// ---------------- pooling (batch is sorted, fp16 agg) ----------------
__global__ __launch_bounds__(128) void k_pool(const _Float16* __restrict__ aggh,
                                              const int* __restrict__ batch,
                                              const float* __restrict__ scale,
                                              const float* __restrict__ shift,
                                              float* pooled, float* cnt, int n) {
    int t = threadIdx.x;
    int row0 = blockIdx.x * POOL_CHUNK;
    if (row0 >= n) return;
    int rend = min(row0 + POOL_CHUNK, n);
    float sc = scale[t], sh = shift[t];
    int gcur = batch[row0];
    float acc = 0.f, c = 0.f;
    for (int r = row0; r < rend; ++r) {
        int g = batch[r];
        if (g != gcur) {
            unsafeAtomicAdd(&pooled[gcur * F + t], acc);
            if (t == 0) unsafeAtomicAdd(&cnt[gcur], c);
            acc = 0.f; c = 0.f; gcur = g;
        }
        float v = fmaxf((float)aggh[(size_t)r * F + t] * sc + sh, 0.f);
        acc += v; c += 1.f;
    }
    unsafeAtomicAdd(&pooled[gcur * F + t], acc);
    if (t == 0) unsafeAtomicAdd(&cnt[gcur], c);
}

// ---------------- final MLP ----------------
__global__ __launch_bounds__(128) void k_mlp(const float* __restrict__ pooled,
                                             const float* __restrict__ cnt,
                                             const float* __restrict__ l1w, const float* __restrict__ l1b,
                                             const float* __restrict__ l2w, const float* __restrict__ l2b,
                                             const float* __restrict__ fcw, const float* __restrict__ fcb,
                                             float* __restrict__ out) {
    __shared__ float pr[F], h1[F], h2[OUTF];
    int g = blockIdx.x, t = threadIdx.x;
    float c = fmaxf(cnt[g], 1.f);
    pr[t] = pooled[g * F + t] / c;
    __syncthreads();
    float a = l1b[t];
#pragma unroll 4
    for (int k = 0; k < F; ++k) a += pr[k] * l1w[k * F + t];
    h1[t] = a;
    __syncthreads();
    if (t < OUTF) {
        float b = l2b[t];
#pragma unroll 4
        for (int k = 0; k < F; ++k) b += h1[k] * l2w[k * OUTF + t];
        h2[t] = b;
    }
    __syncthreads();
    if (t < OUTF) {
        float o = fcb[t];
#pragma unroll 4
        for (int k = 0; k < OUTF; ++k) o += h2[k] * fcw[k * OUTF + t];
        out[g * OUTF + t] = (o >= 0.f) ? o : 0.01f * o;
    }
}

// ---------------- launcher ----------------
extern "C" void kernel_launch(void* const* d_in, const int* in_sizes, int n_in,
                              void* d_out, int out_size, void* d_ws, size_t ws_size,
                              hipStream_t stream) {
    const float* x      = (const float*)d_in[0];
    const int*   ei     = (const int*)d_in[1];
    const int*   batch  = (const int*)d_in[2];
    const float* convw[3] = {(const float*)d_in[3], (const float*)d_in[5], (const float*)d_in[7]};
    const float* convb[3] = {(const float*)d_in[4], (const float*)d_in[6], (const float*)d_in[8]};
    const float* bng[3]   = {(const float*)d_in[9],  (const float*)d_in[11], (const float*)d_in[13]};
    const float* bnb[3]   = {(const float*)d_in[10], (const float*)d_in[12], (const float*)d_in[14]};
    const float* l1w = (const float*)d_in[15]; const float* l1b = (const float*)d_in[16];
    const float* l2w = (const float*)d_in[17]; const float* l2b = (const float*)d_in[18];
    const float* fcw = (const float*)d_in[19]; const float* fcb = (const float*)d_in[20];

    const int N = in_sizes[2];
    const int E = in_sizes[1] / 2;
    const int* srcp = ei;
    const int* dstp = ei + E;
    const int NB = (N + 255) / 256;          // node-scan blocks (196)
    const int NBUCK = (N + 255) >> 8;        // 256-node buckets (196)
    const int HLEN = NBUCK * NP1;            // histogram length (50176)
    const int HB = (HLEN + 255) / 256;       // hist-scan blocks (196, <=256)

    char* wsp = (char*)d_ws;
    size_t off_b = 0;
    auto alloc = [&](size_t bytes) -> void* {
        void* p = wsp + off_b;
        off_b += (bytes + 255) / 256 * 256;
        return p;
    };
    int*      degi    = (int*)alloc((size_t)N * 4);
    float*    dis     = (float*)alloc((size_t)N * 4);
    int*      offs    = (int*)alloc((size_t)(N + 1) * 4);
    int*      cursor  = (int*)alloc((size_t)N * 4);
    int*      bsum    = (int*)alloc(256 * 4);
    int*      hbase   = (int*)alloc((size_t)HLEN * 4);
    int*      bsum2   = (int*)alloc(256 * 4);
    unsigned* tmp     = (unsigned*)alloc((size_t)E * 4);
    unsigned* csr4    = (unsigned*)alloc((size_t)E * 4);
    _Float16* hbuf    = (_Float16*)alloc((size_t)N * F * 2);
    _Float16* aggh    = (_Float16*)alloc((size_t)N * F * 2);
    float*    sum     = (float*)alloc(F * 4);
    float*    sumsq   = (float*)alloc(F * 4);   // contiguous after sum
    float*    scale   = (float*)alloc(F * 4);
    float*    shift   = (float*)alloc(F * 4);
    float*    pooled  = (float*)alloc(NGRAPH * F * 4);
    float*    cnt     = (float*)alloc(NGRAPH * 4);  // contiguous after pooled
    (void)ws_size; (void)n_in; (void)out_size;

    // ---- CSR build: degree -> offsets; radix partition -> exact placement ----
    k_deg_init<<<NB, 256, 0, stream>>>(degi, N);
    k_deg_edges<<<(E + 255) / 256, 256, 0, stream>>>(dstp, degi, E);
    k_scan1<<<NB, 256, 0, stream>>>(degi, offs, bsum, dis, N);
    k_scan2<<<1, 256, 0, stream>>>(bsum, NB);
    k_scan3<<<NB, 256, 0, stream>>>(degi, offs, bsum, cursor, N);

    k_hist<<<NP1, 256, 0, stream>>>(dstp, hbase, E, NBUCK);
    k_scan1<<<HB, 256, 0, stream>>>(hbase, hbase, bsum2, nullptr, HLEN);
    k_scan2<<<1, 256, 0, stream>>>(bsum2, HB);
    k_scan3b<<<HB, 256, 0, stream>>>(hbase, bsum2, HLEN);
    k_part<<<NP1, 256, 0, stream>>>(srcp, dstp, hbase, tmp, E, NBUCK);
    k_scatB<<<NBUCK, 256, 0, stream>>>(tmp, offs, dis, cursor, csr4, N);

    // zero BN accumulators once; k_stats_final re-zeroes them per layer
    k_zero<<<1, 256, 0, stream>>>(sum, 2 * F);

    // ---- 3 GCN layers ----
    const int SB = (N + STAT_ROWS - 1) / STAT_ROWS;
    for (int l = 0; l < 3; ++l) {
        if (l == 0)
            k_gemm_mfma<float><<<(N + 63) / 64, 256, 0, stream>>>(
                x, convw[l], hbuf, scale, shift, N, 0);
        else
            k_gemm_mfma<_Float16><<<(N + 63) / 64, 256, 0, stream>>>(
                aggh, convw[l], hbuf, scale, shift, N, 1);
        k_gcn_agg<<<(N + 15) / 16, 256, 0, stream>>>(hbuf, csr4, offs, dis, convb[l], aggh, N);
        k_stats<<<SB, 256, 0, stream>>>(aggh, sum, sumsq, N);
        k_stats_final<<<1, 128, 0, stream>>>(sum, sumsq, bng[l], bnb[l], scale, shift, N);
    }

    k_zero<<<(NGRAPH * F + NGRAPH + 255) / 256, 256, 0, stream>>>(pooled, NGRAPH * F + NGRAPH);
    k_pool<<<(N + POOL_CHUNK - 1) / POOL_CHUNK, 128, 0, stream>>>(aggh, batch, scale, shift, pooled, cnt, N);
    k_mlp<<<NGRAPH, 128, 0, stream>>>(pooled, cnt, l1w, l1b, l2w, l2b, fcw, fcb, (float*)d_out);
}

// Round 14
// 529.404 us; speedup vs baseline: 2.6786x; 1.1167x over previous
//
#include <hip/hip_runtime.h>
#include <hip/hip_fp16.h>

constexpr int F      = 128;   // IN = H = CLS
constexpr int OUTF   = 64;
constexpr int NGRAPH = 128;
constexpr int POOL_CHUNK = 64;
constexpr int NP1    = 256;   // partition blocks (fixed, must match hist/part)
constexpr int STAT_ROWS = 128;  // rows per stats block

using half8 = __attribute__((ext_vector_type(8))) _Float16;
using f32x4 = __attribute__((ext_vector_type(4))) float;
using f32x8 = __attribute__((ext_vector_type(8))) float;

// ---------------- generic 2-level exclusive scan ----------------
__global__ __launch_bounds__(256) void k_scan1(const int* __restrict__ src,
                                               int* __restrict__ out, int* __restrict__ bsum, int n) {
    __shared__ int tmp[256];
    int i = blockIdx.x * 256 + threadIdx.x;
    int v = (i < n) ? src[i] : 0;
    tmp[threadIdx.x] = v;
    __syncthreads();
    for (int s = 1; s < 256; s <<= 1) {
        int t = (threadIdx.x >= s) ? tmp[threadIdx.x - s] : 0;
        __syncthreads();
        tmp[threadIdx.x] += t;
        __syncthreads();
    }
    if (i < n) out[i] = tmp[threadIdx.x] - v;  // exclusive
    if (threadIdx.x == 255) bsum[blockIdx.x] = tmp[255];
}

__global__ __launch_bounds__(256) void k_scan2(int* bsum, int nb) {
    __shared__ int tmp[256];
    int i = threadIdx.x;
    int v = (i < nb) ? bsum[i] : 0;
    tmp[i] = v;
    __syncthreads();
    for (int s = 1; s < 256; s <<= 1) {
        int t = (i >= s) ? tmp[i - s] : 0;
        __syncthreads();
        tmp[i] += t;
        __syncthreads();
    }
    if (i < nb) bsum[i] = tmp[i] - v;  // exclusive
}

// node-offset finalize: offs, cursor, tail
__global__ __launch_bounds__(256) void k_scan3(const int* __restrict__ degi, int* __restrict__ off,
                                               const int* __restrict__ bsum, int* __restrict__ cursor, int n) {
    int i = blockIdx.x * 256 + threadIdx.x;
    if (i < n) {
        int o = off[i] + bsum[i >> 8];
        off[i] = o;
        cursor[i] = o;
        if (i == n - 1) off[n] = o + degi[i];
    }
}

// generic finalize (for histogram scan)
__global__ __launch_bounds__(256) void k_scan3b(int* __restrict__ arr, const int* __restrict__ bsum, int n) {
    int i = blockIdx.x * 256 + threadIdx.x;
    if (i < n) arr[i] += bsum[i >> 8];
}

// ---------------- radix partition by dst>>8 (bucket = 256 nodes) ----------------
__global__ __launch_bounds__(256) void k_hist(const int* __restrict__ dst,
                                              int* __restrict__ histg, int e, int nbuckets) {
    __shared__ int lh[256];
    lh[threadIdx.x] = 0;
    __syncthreads();
    const int chunk = (e + NP1 - 1) / NP1;
    const int i0 = blockIdx.x * chunk;
    const int i1 = min(i0 + chunk, e);
    for (int i = i0 + threadIdx.x; i < i1; i += 256)
        atomicAdd(&lh[dst[i] >> 8], 1);
    __syncthreads();
    if (threadIdx.x < nbuckets)
        histg[threadIdx.x * NP1 + blockIdx.x] = lh[threadIdx.x];
}

// partition: each (block,bucket) segment written contiguously
__global__ __launch_bounds__(256) void k_part(const int* __restrict__ src, const int* __restrict__ dst,
                                              const int* __restrict__ hbase,
                                              unsigned* __restrict__ tmp, int e, int nbuckets) {
    __shared__ int lc[256];
    if (threadIdx.x < nbuckets)
        lc[threadIdx.x] = hbase[threadIdx.x * NP1 + blockIdx.x];
    __syncthreads();
    const int chunk = (e + NP1 - 1) / NP1;
    const int i0 = blockIdx.x * chunk;
    const int i1 = min(i0 + chunk, e);
    for (int i = i0 + threadIdx.x; i < i1; i += 256) {
        int s = src[i], d = dst[i];
        int pos = atomicAdd(&lc[d >> 8], 1);
        tmp[pos] = ((unsigned)s << 8) | (unsigned)(d & 255);
    }
}

// per-bucket degree count from partitioned tmp (LDS histogram, coalesced writes, no global atomics)
__global__ __launch_bounds__(256) void k_degB(const unsigned* __restrict__ tmp,
                                              const int* __restrict__ hbase,
                                              int* __restrict__ degi, float* __restrict__ dis,
                                              int e, int n, int nbuckets) {
    __shared__ int lh[256];
    lh[threadIdx.x] = 0;
    __syncthreads();
    const int b = blockIdx.x;
    const int j0 = hbase[b * NP1];
    const int j1 = (b + 1 < nbuckets) ? hbase[(b + 1) * NP1] : e;
    for (int j = j0 + threadIdx.x; j < j1; j += 256)
        atomicAdd(&lh[tmp[j] & 255u], 1);
    __syncthreads();
    const int node = (b << 8) + threadIdx.x;
    if (node < n) {
        int dv = lh[threadIdx.x];
        degi[node] = dv;
        dis[node] = rsqrtf((float)(dv + 1));  // +1 self-loop
    }
}

// exact per-node placement within L2-resident 256-node bucket region
__global__ __launch_bounds__(256) void k_scatB(const unsigned* __restrict__ tmp, const int* __restrict__ off,
                                               const float* __restrict__ dis, int* __restrict__ cursor,
                                               unsigned* __restrict__ csr4, int n) {
    int n0 = blockIdx.x << 8;
    int n1 = min(n0 + 256, n);
    int j1 = off[n1];
    for (int j = off[n0] + threadIdx.x; j < j1; j += 256) {
        unsigned v = tmp[j];
        int s = (int)(v >> 8);
        int d = n0 + (int)(v & 255u);
        float nm = dis[s] * dis[d];
        int pos = atomicAdd(&cursor[d], 1);
        unsigned short nh = __builtin_bit_cast(unsigned short, (_Float16)nm);
        csr4[pos] = (unsigned)s | ((unsigned)nh << 16);
    }
}

// ---------------- MFMA GEMM: h = fp16( act(in) @ W ), act = BN+ReLU of prev layer ----------------
template <typename T>
__global__ __launch_bounds__(256) void k_gemm_mfma(const T* __restrict__ in,
                                                   const float* __restrict__ w,
                                                   _Float16* __restrict__ out,
                                                   const float* __restrict__ scale,
                                                   const float* __restrict__ shift,
                                                   int n, int apply) {
    __shared__ _Float16 wt[F][F + 8];
    const int t = threadIdx.x;
#pragma unroll
    for (int r = 0; r < 64; ++r) {
        int idx = r * 256 + t;
        int k = idx >> 7, nn = idx & (F - 1);
        wt[nn][k] = (_Float16)w[idx];
    }
    __syncthreads();

    const int wave = t >> 6, lane = t & 63;
    const int row0 = blockIdx.x * 64 + wave * 16;
    const int arow = row0 + (lane & 15);
    const int kblk = (lane >> 4) * 8;
    const bool rvalid = arow < n;

    f32x4 acc[8];
#pragma unroll
    for (int nt = 0; nt < 8; ++nt) acc[nt] = (f32x4){0.f, 0.f, 0.f, 0.f};

#pragma unroll
    for (int ks = 0; ks < 4; ++ks) {
        const int k0 = ks * 32 + kblk;
        half8 afrag;
        if (rvalid) {
            float av[8];
            if constexpr (sizeof(T) == 4) {
                f32x8 v = *(const f32x8*)&in[(size_t)arow * F + k0];
#pragma unroll
                for (int i = 0; i < 8; ++i) av[i] = v[i];
            } else {
                half8 v = *(const half8*)&in[(size_t)arow * F + k0];
#pragma unroll
                for (int i = 0; i < 8; ++i) av[i] = (float)v[i];
            }
            if (apply) {
                f32x8 sc = *(const f32x8*)&scale[k0];
                f32x8 sh = *(const f32x8*)&shift[k0];
#pragma unroll
                for (int i = 0; i < 8; ++i) av[i] = fmaxf(av[i] * sc[i] + sh[i], 0.f);
            }
#pragma unroll
            for (int i = 0; i < 8; ++i) afrag[i] = (_Float16)av[i];
        } else {
#pragma unroll
            for (int i = 0; i < 8; ++i) afrag[i] = (_Float16)0.f;
        }
#pragma unroll
        for (int nt = 0; nt < 8; ++nt) {
            const half8 bfrag = *(const half8*)&wt[nt * 16 + (lane & 15)][k0];
            acc[nt] = __builtin_amdgcn_mfma_f32_16x16x32_f16(afrag, bfrag, acc[nt], 0, 0, 0);
        }
    }

    const int orow = row0 + (lane >> 4) * 4;
    const int ocol = lane & 15;
#pragma unroll
    for (int i = 0; i < 4; ++i) {
        if (orow + i < n) {
            _Float16* op = &out[(size_t)(orow + i) * F + ocol];
#pragma unroll
            for (int nt = 0; nt < 8; ++nt) op[nt * 16] = (_Float16)acc[nt][i];
        }
    }
}

// ---------------- aggregation: pure gather-reduce (4x unrolled), fp16 h -> fp16 agg ----------------
__global__ __launch_bounds__(256) void k_gcn_agg(const _Float16* __restrict__ h,
                                                 const unsigned* __restrict__ csr4,
                                                 const int* __restrict__ off,
                                                 const float* __restrict__ dis,
                                                 const float* __restrict__ bias,
                                                 _Float16* __restrict__ aggh, int n) {
    const int t = threadIdx.x;
    const int node = blockIdx.x * 16 + (t >> 4);
    if (node >= n) return;
    const int f0 = (t & 15) << 3;
    float d = dis[node];
    float dd = d * d;
    const half8 hv0 = *(const half8*)&h[(size_t)node * F + f0];
    float acc[8];
#pragma unroll
    for (int i = 0; i < 8; ++i) acc[i] = (float)hv0[i] * dd + bias[f0 + i];

    int k = off[node];
    const int k1 = off[node + 1];
    for (; k + 3 < k1; k += 4) {
        unsigned u0 = __builtin_nontemporal_load(&csr4[k]);
        unsigned u1 = __builtin_nontemporal_load(&csr4[k + 1]);
        unsigned u2 = __builtin_nontemporal_load(&csr4[k + 2]);
        unsigned u3 = __builtin_nontemporal_load(&csr4[k + 3]);
        int s0 = (int)(u0 & 0xFFFFu), s1 = (int)(u1 & 0xFFFFu);
        int s2 = (int)(u2 & 0xFFFFu), s3 = (int)(u3 & 0xFFFFu);
        float nm0 = (float)__builtin_bit_cast(_Float16, (unsigned short)(u0 >> 16));
        float nm1 = (float)__builtin_bit_cast(_Float16, (unsigned short)(u1 >> 16));
        float nm2 = (float)__builtin_bit_cast(_Float16, (unsigned short)(u2 >> 16));
        float nm3 = (float)__builtin_bit_cast(_Float16, (unsigned short)(u3 >> 16));
        const half8 a = *(const half8*)&h[(size_t)s0 * F + f0];
        const half8 b = *(const half8*)&h[(size_t)s1 * F + f0];
        const half8 c = *(const half8*)&h[(size_t)s2 * F + f0];
        const half8 e = *(const half8*)&h[(size_t)s3 * F + f0];
#pragma unroll
        for (int i = 0; i < 8; ++i) acc[i] += (float)a[i] * nm0;
#pragma unroll
        for (int i = 0; i < 8; ++i) acc[i] += (float)b[i] * nm1;
#pragma unroll
        for (int i = 0; i < 8; ++i) acc[i] += (float)c[i] * nm2;
#pragma unroll
        for (int i = 0; i < 8; ++i) acc[i] += (float)e[i] * nm3;
    }
    for (; k < k1; ++k) {
        unsigned u0 = __builtin_nontemporal_load(&csr4[k]);
        int s0 = (int)(u0 & 0xFFFFu);
        float nm0 = (float)__builtin_bit_cast(_Float16, (unsigned short)(u0 >> 16));
        const half8 a = *(const half8*)&h[(size_t)s0 * F + f0];
#pragma unroll
        for (int i = 0; i < 8; ++i) acc[i] += (float)a[i] * nm0;
    }
    half8 res;
#pragma unroll
    for (int i = 0; i < 8; ++i) res[i] = (_Float16)acc[i];
    *(half8*)&aggh[(size_t)node * F + f0] = res;
}

// ---------------- batchnorm stats: streaming column reduce (256 thr, 128 rows/block) ----------------
__global__ __launch_bounds__(256) void k_stats(const _Float16* __restrict__ aggh,
                                               float* __restrict__ sum,
                                               float* __restrict__ sumsq, int n) {
    __shared__ float ls[F], lq[F];
    const int t = threadIdx.x;
    const int col = t & (F - 1);
    const int row0 = blockIdx.x * STAT_ROWS + (t >> 7);  // two row-streams per block
    const int rend = min(blockIdx.x * STAT_ROWS + STAT_ROWS, n);
    float s = 0.f, q = 0.f;
    for (int r = row0; r < rend; r += 2) {
        float v = (float)aggh[(size_t)r * F + col];
        s += v; q += v * v;
    }
    if (t >= F) { ls[col] = s; lq[col] = q; }
    __syncthreads();
    if (t < F) {
        s += ls[col]; q += lq[col];
        unsafeAtomicAdd(&sum[col], s);
        unsafeAtomicAdd(&sumsq[col], q);
    }
}

// ---------------- batchnorm finalize (self-zeroing accumulators) ----------------
__global__ __launch_bounds__(256) void k_zero(float* p, int n) {
    int i = blockIdx.x * 256 + threadIdx.x;
    if (i < n) p[i] = 0.f;
}

__global__ __launch_bounds__(128) void k_stats_final(float* __restrict__ sum,
                                                     float* __restrict__ sumsq,
                                                     const float* __restrict__ g,
                                                     const float* __restrict__ b,
                                                     float* scale, float* shift, int n) {
    int t = threadIdx.x;
    float mean = sum[t] / (float)n;
    float var = fmaxf(sumsq[t] / (float)n - mean * mean, 0.f);
    float inv = rsqrtf(var + 1e-5f);
    float sc = g[t] * inv;
    scale[t] = sc;
    shift[t] = b[t] - mean * sc;
    sum[t] = 0.f;     // ready for next layer
    sumsq[t] = 0.f;
}

// ---------------- pooling (batch is sorted, fp16 agg) ----------------
__global__ __launch_bounds__(128) void k_pool(const _Float16* __restrict__ aggh,
                                              const int* __restrict__ batch,
                                              const float* __restrict__ scale,
                                              const float* __restrict__ shift,
                                              float* pooled, float* cnt, int n) {
    int t = threadIdx.x;
    int row0 = blockIdx.x * POOL_CHUNK;
    if (row0 >= n) return;
    int rend = min(row0 + POOL_CHUNK, n);
    float sc = scale[t], sh = shift[t];
    int gcur = batch[row0];
    float acc = 0.f, c = 0.f;
    for (int r = row0; r < rend; ++r) {
        int g = batch[r];
        if (g != gcur) {
            unsafeAtomicAdd(&pooled[gcur * F + t], acc);
            if (t == 0) unsafeAtomicAdd(&cnt[gcur], c);
            acc = 0.f; c = 0.f; gcur = g;
        }
        float v = fmaxf((float)aggh[(size_t)r * F + t] * sc + sh, 0.f);
        acc += v; c += 1.f;
    }
    unsafeAtomicAdd(&pooled[gcur * F + t], acc);
    if (t == 0) unsafeAtomicAdd(&cnt[gcur], c);
}

// ---------------- final MLP ----------------
__global__ __launch_bounds__(128) void k_mlp(const float* __restrict__ pooled,
                                             const float* __restrict__ cnt,
                                             const float* __restrict__ l1w, const float* __restrict__ l1b,
                                             const float* __restrict__ l2w, const float* __restrict__ l2b,
                                             const float* __restrict__ fcw, const float* __restrict__ fcb,
                                             float* __restrict__ out) {
    __shared__ float pr[F], h1[F], h2[OUTF];
    int g = blockIdx.x, t = threadIdx.x;
    float c = fmaxf(cnt[g], 1.f);
    pr[t] = pooled[g * F + t] / c;
    __syncthreads();
    float a = l1b[t];
#pragma unroll 4
    for (int k = 0; k < F; ++k) a += pr[k] * l1w[k * F + t];
    h1[t] = a;
    __syncthreads();
    if (t < OUTF) {
        float b = l2b[t];
#pragma unroll 4
        for (int k = 0; k < F; ++k) b += h1[k] * l2w[k * OUTF + t];
        h2[t] = b;
    }
    __syncthreads();
    if (t < OUTF) {
        float o = fcb[t];
#pragma unroll 4
        for (int k = 0; k < OUTF; ++k) o += h2[k] * fcw[k * OUTF + t];
        out[g * OUTF + t] = (o >= 0.f) ? o : 0.01f * o;
    }
}

// ---------------- launcher ----------------
extern "C" void kernel_launch(void* const* d_in, const int* in_sizes, int n_in,
                              void* d_out, int out_size, void* d_ws, size_t ws_size,
                              hipStream_t stream) {
    const float* x      = (const float*)d_in[0];
    const int*   ei     = (const int*)d_in[1];
    const int*   batch  = (const int*)d_in[2];
    const float* convw[3] = {(const float*)d_in[3], (const float*)d_in[5], (const float*)d_in[7]};
    const float* convb[3] = {(const float*)d_in[4], (const float*)d_in[6], (const float*)d_in[8]};
    const float* bng[3]   = {(const float*)d_in[9],  (const float*)d_in[11], (const float*)d_in[13]};
    const float* bnb[3]   = {(const float*)d_in[10], (const float*)d_in[12], (const float*)d_in[14]};
    const float* l1w = (const float*)d_in[15]; const float* l1b = (const float*)d_in[16];
    const float* l2w = (const float*)d_in[17]; const float* l2b = (const float*)d_in[18];
    const float* fcw = (const float*)d_in[19]; const float* fcb = (const float*)d_in[20];

    const int N = in_sizes[2];
    const int E = in_sizes[1] / 2;
    const int* srcp = ei;
    const int* dstp = ei + E;
    const int NB = (N + 255) / 256;          // node-scan blocks (196)
    const int NBUCK = (N + 255) >> 8;        // 256-node buckets (196)
    const int HLEN = NBUCK * NP1;            // histogram length (50176)
    const int HB = (HLEN + 255) / 256;       // hist-scan blocks (196, <=256)

    char* wsp = (char*)d_ws;
    size_t off_b = 0;
    auto alloc = [&](size_t bytes) -> void* {
        void* p = wsp + off_b;
        off_b += (bytes + 255) / 256 * 256;
        return p;
    };
    int*      degi    = (int*)alloc((size_t)N * 4);
    float*    dis     = (float*)alloc((size_t)N * 4);
    int*      offs    = (int*)alloc((size_t)(N + 1) * 4);
    int*      cursor  = (int*)alloc((size_t)N * 4);
    int*      bsum    = (int*)alloc(256 * 4);
    int*      hbase   = (int*)alloc((size_t)HLEN * 4);
    int*      bsum2   = (int*)alloc(256 * 4);
    unsigned* tmp     = (unsigned*)alloc((size_t)E * 4);
    unsigned* csr4    = (unsigned*)alloc((size_t)E * 4);
    _Float16* hbuf    = (_Float16*)alloc((size_t)N * F * 2);
    _Float16* aggh    = (_Float16*)alloc((size_t)N * F * 2);
    float*    sum     = (float*)alloc(F * 4);
    float*    sumsq   = (float*)alloc(F * 4);   // contiguous after sum
    float*    scale   = (float*)alloc(F * 4);
    float*    shift   = (float*)alloc(F * 4);
    float*    pooled  = (float*)alloc(NGRAPH * F * 4);
    float*    cnt     = (float*)alloc(NGRAPH * 4);  // contiguous after pooled
    (void)ws_size; (void)n_in; (void)out_size;

    // ---- CSR build: hist -> partition -> per-bucket degree -> offsets -> placement ----
    k_hist<<<NP1, 256, 0, stream>>>(dstp, hbase, E, NBUCK);
    k_scan1<<<HB, 256, 0, stream>>>(hbase, hbase, bsum2, HLEN);
    k_scan2<<<1, 256, 0, stream>>>(bsum2, HB);
    k_scan3b<<<HB, 256, 0, stream>>>(hbase, bsum2, HLEN);
    k_part<<<NP1, 256, 0, stream>>>(srcp, dstp, hbase, tmp, E, NBUCK);
    k_degB<<<NBUCK, 256, 0, stream>>>(tmp, hbase, degi, dis, E, N, NBUCK);

    k_scan1<<<NB, 256, 0, stream>>>(degi, offs, bsum, N);
    k_scan2<<<1, 256, 0, stream>>>(bsum, NB);
    k_scan3<<<NB, 256, 0, stream>>>(degi, offs, bsum, cursor, N);
    k_scatB<<<NBUCK, 256, 0, stream>>>(tmp, offs, dis, cursor, csr4, N);

    // zero BN accumulators once; k_stats_final re-zeroes them per layer
    k_zero<<<1, 256, 0, stream>>>(sum, 2 * F);

    // ---- 3 GCN layers ----
    const int SB = (N + STAT_ROWS - 1) / STAT_ROWS;
    for (int l = 0; l < 3; ++l) {
        if (l == 0)
            k_gemm_mfma<float><<<(N + 63) / 64, 256, 0, stream>>>(
                x, convw[l], hbuf, scale, shift, N, 0);
        else
            k_gemm_mfma<_Float16><<<(N + 63) / 64, 256, 0, stream>>>(
                aggh, convw[l], hbuf, scale, shift, N, 1);
        k_gcn_agg<<<(N + 15) / 16, 256, 0, stream>>>(hbuf, csr4, offs, dis, convb[l], aggh, N);
        k_stats<<<SB, 256, 0, stream>>>(aggh, sum, sumsq, N);
        k_stats_final<<<1, 128, 0, stream>>>(sum, sumsq, bng[l], bnb[l], scale, shift, N);
    }

    k_zero<<<(NGRAPH * F + NGRAPH + 255) / 256, 256, 0, stream>>>(pooled, NGRAPH * F + NGRAPH);
    k_pool<<<(N + POOL_CHUNK - 1) / POOL_CHUNK, 128, 0, stream>>>(aggh, batch, scale, shift, pooled, cnt, N);
    k_mlp<<<NGRAPH, 128, 0, stream>>>(pooled, cnt, l1w, l1b, l2w, l2b, fcw, fcb, (float*)d_out);
}